// Round 16
// baseline (47.101 us; speedup 1.0000x reference)
//
#include <hip/hip_runtime.h>

#define HH 160
#define WW 160
#define CC 32
#define NN 8
#define PIX (HH * WW)   // 25600

typedef float f32x2 __attribute__((ext_vector_type(2)));

// Burst-length test at iso-occupancy with R13 (31.7us best).
// Block: 320 threads = 2 consecutive h-rows x 160 w; 8 channels/thread
// (per-thread code byte-identical to R13's allocator-proven layout).
// Each block writes FOUR consecutive output rows (4*1280 B = 5120 B
// contiguous per plane) instead of two -> 2x HBM write burst length.
// kv staged for both rows: 46 KB LDS (3 blocks/CU, same waves/CU as R13).
// Grid (80 h-pairs XCD-swizzled, 4 channel-quarters, 8 n).
__global__ __launch_bounds__(320) void pixelconv_k(
    const float* __restrict__ feature,   // [8,32,160,160]
    const float* __restrict__ kern,      // [8,36,160,160]
    float* __restrict__ out)             // [8,32,320,320]
{
    const int bp = blockIdx.x;                       // 0..79 h-pair
    const int h0 = 2 * ((bp & 7) * 10 + (bp >> 3));  // XCD-chunked, even
    const int q  = blockIdx.y;                       // 0..3 channel quarter
    const int n  = blockIdx.z;                       // 0..7
    const int t  = threadIdx.x;                      // 0..319
    const int wl = t % 160;                          // w position
    const int hl = t / 160;                          // 0..1 row within pair

    // ---- stage kernel[n][0:36][h0:h0+2][0:160] into LDS (f32x2, 18 it) ----
    __shared__ float kv_lds[2 * 36 * 160];           // 46080 B
    const float* kb = kern + (size_t)n * 36 * PIX + (size_t)h0 * WW;
    #pragma unroll
    for (int r = 0; r < 18; ++r) {
        const int e   = t + r * 320;                 // 0..5759 (f32x2 elems)
        const int row = e / 80;                      // 0..71 = j*2 + hh
        const int w2  = e - row * 80;
        const int j   = row >> 1;
        const int hh  = row & 1;
        f32x2 v = *(const f32x2*)(kb + (size_t)j * PIX + (size_t)hh * WW + 2 * w2);
        *(f32x2*)&kv_lds[(hh * 36 + j) * 160 + 2 * w2] = v;
    }
    __syncthreads();

    // per-thread copy of the 36 taps for its (h,w) pixel
    float kv[36];
    #pragma unroll
    for (int j = 0; j < 36; ++j) kv[j] = kv_lds[(hl * 36 + j) * 160 + wl];

    const int h = h0 + hl;
    const bool hm = (h > 0), hp = (h < HH - 1);
    const bool wm = (wl > 0), wp = (wl < WW - 1);

    const int cbase = q * 8;
    const float* fc = feature + ((size_t)(n * CC + cbase)) * PIX
                              + (size_t)h * WW + wl;
    float* oc = out + ((size_t)(n * CC + cbase)) * 4 * PIX
                    + (size_t)(2 * h) * (2 * WW) + 2 * wl;

    #pragma unroll 2
    for (int i = 0; i < 8; ++i) {
        // 9 taps, k = dx*3 + dy -> feature[h+dy-1][w+dx-1], imm offsets
        float f[9];
        #pragma unroll
        for (int dx = 0; dx < 3; ++dx) {
            #pragma unroll
            for (int dy = 0; dy < 3; ++dy) {
                const bool ok = (dy != 0 || hm) && (dy != 2 || hp) &&
                                (dx != 0 || wm) && (dx != 2 || wp);
                f[dx * 3 + dy] = ok ? fc[(dy - 1) * WW + (dx - 1)] : 0.0f;
            }
        }

        float a0 = 0.f, a1 = 0.f, a2 = 0.f, a3 = 0.f;
        #pragma unroll
        for (int k = 0; k < 9; ++k) {
            a0 = fmaf(f[k], kv[4 * k + 0], a0);
            a1 = fmaf(f[k], kv[4 * k + 1], a1);
            a2 = fmaf(f[k], kv[4 * k + 2], a2);
            a3 = fmaf(f[k], kv[4 * k + 3], a3);
        }

        // pixel shuffle: s = r1*2 + r2 -> rows 2h (offset 0) and 2h+1 (+320)
        *(f32x2*)(oc)          = (f32x2){a0, a1};
        *(f32x2*)(oc + 2 * WW) = (f32x2){a2, a3};

        fc += PIX;               // next channel's feature plane
        oc += (size_t)4 * PIX;   // next channel's output plane
    }
}

extern "C" void kernel_launch(void* const* d_in, const int* in_sizes, int n_in,
                              void* d_out, int out_size, void* d_ws, size_t ws_size,
                              hipStream_t stream) {
    const float* feature = (const float*)d_in[0];
    const float* kern    = (const float*)d_in[1];
    float* out           = (float*)d_out;

    dim3 grid(80, 4, NN);   // (80 h-pairs, 4 channel-quarters, 8 n)
    pixelconv_k<<<grid, 320, 0, stream>>>(feature, kern, out);
}

// Round 17
// 44.726 us; speedup vs baseline: 1.0531x; 1.0531x over previous
//
#include <hip/hip_runtime.h>

#define HH 160
#define WW 160
#define CC 32
#define NN 8
#define PIX (HH * WW)   // 25600

typedef float f32x2 __attribute__((ext_vector_type(2)));

// Burst-length test, allocator-safe edition. Block: 320 thr = 2 h-rows x
// 160 w; each thread 8 channels (per-thread compute byte-identical to R13's
// proven 31.7us layout). Each block writes 4 consecutive output rows =
// 5120 B contiguous per plane (2x R13's burst). Staging is a PURE LINEAR
// copy -- kv_lds[t + r*320] = kb[r*PIX + t] -- zero index math (R15's f32x2
// staging arithmetic is what blew the register budget). kv read is
// kv_lds[j*320 + t]: consecutive lanes -> conflict-free. 46 KB LDS ->
// 3 blocks/CU = 15 waves/CU, iso-occupancy with R13.
__global__ __launch_bounds__(320) void pixelconv_k(
    const float* __restrict__ feature,   // [8,32,160,160]
    const float* __restrict__ kern,      // [8,36,160,160]
    float* __restrict__ out)             // [8,32,320,320]
{
    const int bp = blockIdx.x;                       // 0..79 h-pair
    const int h0 = 2 * ((bp & 7) * 10 + (bp >> 3));  // XCD-chunked, even
    const int q  = blockIdx.y;                       // 0..3 channel quarter
    const int n  = blockIdx.z;                       // 0..7
    const int t  = threadIdx.x;                      // 0..319
    const int wl = t % 160;                          // w position
    const int hl = t / 160;                          // 0..1 row within pair

    // ---- stage kernel[n][0:36][h0:h0+2][0:160]: pure linear copy ----
    // t = hl*160 + wl maps 1:1 onto hh*WW + ws (WW == 160), so LDS index
    // equals flat source index: no div/mod anywhere.
    __shared__ float kv_lds[36 * 320];               // 46080 B
    const float* kb = kern + (size_t)n * 36 * PIX + (size_t)h0 * WW;
    #pragma unroll
    for (int r = 0; r < 36; ++r)
        kv_lds[t + r * 320] = kb[(size_t)r * PIX + t];
    __syncthreads();

    // per-thread copy of the 36 taps for its (h,w) pixel (lane-consecutive)
    float kv[36];
    #pragma unroll
    for (int j = 0; j < 36; ++j) kv[j] = kv_lds[j * 320 + t];

    const int h = h0 + hl;
    const bool hm = (h > 0), hp = (h < HH - 1);
    const bool wm = (wl > 0), wp = (wl < WW - 1);

    const int cbase = q * 8;
    const float* fc = feature + ((size_t)(n * CC + cbase)) * PIX
                              + (size_t)h * WW + wl;
    float* oc = out + ((size_t)(n * CC + cbase)) * 4 * PIX
                    + (size_t)(2 * h) * (2 * WW) + 2 * wl;

    #pragma unroll 2
    for (int i = 0; i < 8; ++i) {
        // 9 taps, k = dx*3 + dy -> feature[h+dy-1][w+dx-1], imm offsets
        float f[9];
        #pragma unroll
        for (int dx = 0; dx < 3; ++dx) {
            #pragma unroll
            for (int dy = 0; dy < 3; ++dy) {
                const bool ok = (dy != 0 || hm) && (dy != 2 || hp) &&
                                (dx != 0 || wm) && (dx != 2 || wp);
                f[dx * 3 + dy] = ok ? fc[(dy - 1) * WW + (dx - 1)] : 0.0f;
            }
        }

        float a0 = 0.f, a1 = 0.f, a2 = 0.f, a3 = 0.f;
        #pragma unroll
        for (int k = 0; k < 9; ++k) {
            a0 = fmaf(f[k], kv[4 * k + 0], a0);
            a1 = fmaf(f[k], kv[4 * k + 1], a1);
            a2 = fmaf(f[k], kv[4 * k + 2], a2);
            a3 = fmaf(f[k], kv[4 * k + 3], a3);
        }

        // pixel shuffle: s = r1*2 + r2 -> rows 2h (offset 0) and 2h+1 (+320)
        *(f32x2*)(oc)          = (f32x2){a0, a1};
        *(f32x2*)(oc + 2 * WW) = (f32x2){a2, a3};

        fc += PIX;               // next channel's feature plane
        oc += (size_t)4 * PIX;   // next channel's output plane
    }
}

extern "C" void kernel_launch(void* const* d_in, const int* in_sizes, int n_in,
                              void* d_out, int out_size, void* d_ws, size_t ws_size,
                              hipStream_t stream) {
    const float* feature = (const float*)d_in[0];
    const float* kern    = (const float*)d_in[1];
    float* out           = (float*)d_out;

    dim3 grid(80, 4, NN);   // (80 h-pairs, 4 channel-quarters, 8 n)
    pixelconv_k<<<grid, 320, 0, stream>>>(feature, kern, out);
}

// Round 18
// 31.583 us; speedup vs baseline: 1.4914x; 1.4162x over previous
//
#include <hip/hip_runtime.h>

#define HH 160
#define WW 160
#define CC 32
#define NN 8
#define PIX (HH * WW)   // 25600

typedef float f32x2 __attribute__((ext_vector_type(2)));

// FINAL: R13/R14 structure — best measured (31.6-31.7 us, ~4.2 TB/s
// effective on a 21%R/79%W stream). 320-thr blocks (160 w x 2 cg), full-row
// write coherence (the +29% win, R6), XCD-swizzled h, kv[36] resident via
// LDS->VGPR (the only allocator-cooperative layout; 8 restructure attempts
// all triggered spill/remat), f32x2 stores, 8-wave/EU launch bounds.
__global__ __launch_bounds__(320, 8) void pixelconv_k(
    const float* __restrict__ feature,   // [8,32,160,160]
    const float* __restrict__ kern,      // [8,36,160,160]
    float* __restrict__ out)             // [8,32,320,320]
{
    const int bx = blockIdx.x;                 // 0..159
    const int h  = (bx & 7) * 20 + (bx >> 3);  // XCD-chunked h swizzle
    const int chalf = blockIdx.y;              // 0..1 (16 channels each)
    const int n  = blockIdx.z;                 // 0..7
    const int t  = threadIdx.x;                // 0..319
    const int wl = t % 160;                    // w position
    const int cg = t / 160;                    // 0..1 channel group (8 ch)

    // ---- stage kernel[n][0:36][h][0:160] into LDS (18 iters, coalesced) ----
    __shared__ float kv_lds[36 * 160];
    const float* kbase = kern + (size_t)n * 36 * PIX + (size_t)h * WW;
    #pragma unroll
    for (int r = 0; r < 18; ++r) {
        const int idx = t + r * 320;           // 5760 = 18 * 320 exactly
        const int j   = idx / 160;
        const int ws  = idx - j * 160;
        kv_lds[idx] = kbase[(size_t)j * PIX + ws];
    }
    __syncthreads();

    // per-thread copy of the 36 taps for its pixel (bank-conflict-free)
    float kv[36];
    #pragma unroll
    for (int j = 0; j < 36; ++j) kv[j] = kv_lds[j * 160 + wl];

    const bool hm = (h > 0), hp = (h < HH - 1);
    const bool wm = (wl > 0), wp = (wl < WW - 1);

    const int cbase = chalf * 16 + cg * 8;
    const float* fc = feature + ((size_t)(n * CC + cbase)) * PIX
                              + (size_t)h * WW + wl;
    float* oc = out + ((size_t)(n * CC + cbase)) * 4 * PIX
                    + (size_t)(2 * h) * (2 * WW) + 2 * wl;

    #pragma unroll 1
    for (int i = 0; i < 8; ++i) {
        // 9 taps, k = dx*3 + dy -> feature[h+dy-1][w+dx-1], imm offsets
        float f[9];
        #pragma unroll
        for (int dx = 0; dx < 3; ++dx) {
            #pragma unroll
            for (int dy = 0; dy < 3; ++dy) {
                const bool ok = (dy != 0 || hm) && (dy != 2 || hp) &&
                                (dx != 0 || wm) && (dx != 2 || wp);
                f[dx * 3 + dy] = ok ? fc[(dy - 1) * WW + (dx - 1)] : 0.0f;
            }
        }

        float a0 = 0.f, a1 = 0.f, a2 = 0.f, a3 = 0.f;
        #pragma unroll
        for (int k = 0; k < 9; ++k) {
            a0 = fmaf(f[k], kv[4 * k + 0], a0);
            a1 = fmaf(f[k], kv[4 * k + 1], a1);
            a2 = fmaf(f[k], kv[4 * k + 2], a2);
            a3 = fmaf(f[k], kv[4 * k + 3], a3);
        }

        // pixel shuffle: s = r1*2 + r2 -> rows 2h (offset 0) and 2h+1 (+320)
        *(f32x2*)(oc)          = (f32x2){a0, a1};
        *(f32x2*)(oc + 2 * WW) = (f32x2){a2, a3};

        fc += PIX;               // next channel's feature plane
        oc += (size_t)4 * PIX;   // next channel's output plane
    }
}

extern "C" void kernel_launch(void* const* d_in, const int* in_sizes, int n_in,
                              void* d_out, int out_size, void* d_ws, size_t ws_size,
                              hipStream_t stream) {
    const float* feature = (const float*)d_in[0];
    const float* kern    = (const float*)d_in[1];
    float* out           = (float*)d_out;

    dim3 grid(HH, 2, NN);   // (160 h, 2 channel-half, 8 n)
    pixelconv_k<<<grid, 320, 0, stream>>>(feature, kern, out);
}